// Round 5
// baseline (627.980 us; speedup 1.0000x reference)
//
#include <hip/hip_runtime.h>

#define NT 128      // num tags
#define SEQ 1024    // sequence length
#define NB 256      // batch

typedef _Float16 half2v __attribute__((ext_vector_type(2)));

// One DPP max step on the VALU pipe (no DS/lgkmcnt involvement).
#define DPP_MAX_STEP(x, ctrl)                                                   \
    fmaxf((x), __builtin_bit_cast(float, __builtin_amdgcn_update_dpp(           \
        __builtin_bit_cast(int, (x)), __builtin_bit_cast(int, (x)),             \
        (ctrl), 0xf, 0xf, false)))

__device__ __forceinline__ float wave_max_dpp(float x) {
    x = DPP_MAX_STEP(x, 0x111);   // row_shr:1
    x = DPP_MAX_STEP(x, 0x112);   // row_shr:2
    x = DPP_MAX_STEP(x, 0x114);   // row_shr:4
    x = DPP_MAX_STEP(x, 0x118);   // row_shr:8
    x = DPP_MAX_STEP(x, 0x142);   // row_bcast:15
    x = DPP_MAX_STEP(x, 0x143);   // row_bcast:31
    return __builtin_bit_cast(float, __builtin_amdgcn_readlane(
        __builtin_bit_cast(int, x), 63));
}

// lane[i] + lane[i^32] on the VALU pipe (v_permlane32_swap_b32, gfx950).
// With a=b=x, after the swap a+b == x[i&31] + x[(i&31)+32] in every lane.
__device__ __forceinline__ float cross32_add(float x) {
    float a = x, b = x;
    asm volatile("v_permlane32_swap_b32 %0, %1" : "+v"(a), "+v"(b));
    return a + b;
}

// lane[i] + lane[i^16] on the VALU pipe (v_permlane16_swap_b32, gfx950).
// Swaps odd 16-lane rows of dst0 with even rows of dst1; with a=b=x every
// lane ends with {x[row even], x[row odd]} of its 32-half -> a+b is the
// pairwise i^16 sum in all lanes.
__device__ __forceinline__ float cross16_add(float x) {
    float a = x, b = x;
    asm volatile("v_permlane16_swap_b32 %0, %1" : "+v"(a), "+v"(b));
    return a + b;
}

// lane[i^1] via DPP quad_perm [1,0,3,2] (ctrl 0xB1) -- VALU, exact.
__device__ __forceinline__ float swap1_dpp(float x) {
    return __builtin_bit_cast(float, __builtin_amdgcn_update_dpp(
        0, __builtin_bit_cast(int, x), 0xB1, 0xf, 0xf, true));
}

// One scan step, 8-wave cooperative version (2 waves per SIMD).
// Wave w owns columns [16w,16w+16); lane: col c=16w+(l&15), K-quarter
// kq=l>>4 covering i in [32kq, 32kq+32). P lives in LDS as packed f16
// pairs (64 uints), double-buffered (BUF). One __syncthreads per step
// (ping-pong, reads of BUF precede the barrier, writes of BUF^1 follow it).
// Column reduce over the 4 K-quarters = cross16_add + cross32_add (VALU).
#define CRF_STEP(RC, RN, MC, DO_PRE, K, BUF)                                     \
    {                                                                            \
        float mcur = MC;                                                         \
        if (DO_PRE) { RC = emp[(K) * NT]; MC = mpp[K]; }                         \
        float eRN = __expf(RN);          /* hoisted off the post-barrier path */ \
        const uint4* p4 = (const uint4*)&p_lds[BUF][16 * kq];                    \
        float A0=0.f, A1=0.f, A2=0.f, A3=0.f;                                    \
        _Pragma("unroll")                                                        \
        for (int qi = 0; qi < 4; ++qi) {                                         \
            uint4 q = p4[qi];                                                    \
            A0 = __builtin_amdgcn_fdot2(__builtin_bit_cast(half2v, q.x),         \
                                        E[4*qi+0], A0, false);                   \
            A1 = __builtin_amdgcn_fdot2(__builtin_bit_cast(half2v, q.y),         \
                                        E[4*qi+1], A1, false);                   \
            A2 = __builtin_amdgcn_fdot2(__builtin_bit_cast(half2v, q.z),         \
                                        E[4*qi+2], A2, false);                   \
            A3 = __builtin_amdgcn_fdot2(__builtin_bit_cast(half2v, q.w),         \
                                        E[4*qi+3], A3, false);                   \
        }                                                                        \
        float part = (A0 + A1) + (A2 + A3);                                      \
        float sv = cross32_add(cross16_add(part));                               \
        float v = sv * ex;                                                       \
        if (mcur > 0.0f) { cur = v; offset += offadd; }                          \
        float curo = swap1_dpp(cur);     /* partner column for f16 pack */       \
        if (kq == 0 && (cl & 1) == 0)                                            \
            p_lds[(BUF)^1][8*w + (cl >> 1)] = __builtin_bit_cast(unsigned int,   \
                __builtin_amdgcn_cvt_pkrtz(cur, curo));                          \
        float wm = wave_max_dpp(cur);                                            \
        if (l == 0) wmax[(BUF)^1][w] = wm;                                       \
        __syncthreads();                                                         \
        float4 wa = *(const float4*)&wmax[(BUF)^1][0];                           \
        float4 wb = *(const float4*)&wmax[(BUF)^1][4];                           \
        mx = fmaxf(fmaxf(fmaxf(wa.x, wa.y), fmaxf(wa.z, wa.w)),                  \
                   fmaxf(fmaxf(wb.x, wb.y), fmaxf(wb.z, wb.w)));                 \
        inv = __builtin_amdgcn_rcpf(256.0f * mx);                                \
        offadd = __logf(mx) + 5.545177444479562f;                                \
        ex = eRN * inv;                                                          \
    }

// EIGHT WAVES per batch element (2 per SIMD). 256 blocks x 512 threads.
// Same total issue and DS volume as the 4-wave version, but each SIMD now
// hosts two waves of the lockstep pipeline: one wave's dependency gaps
// (ds_read latency, fdot2 chain, DPP max chain) are filled by the other.
__global__ __launch_bounds__(512, 1) void crf_scan_kernel(
    const float* __restrict__ emissions,    // [B,S,T]
    const float* __restrict__ masks,        // [B,S]
    const int*   __restrict__ tags,         // [B,S]
    const float* __restrict__ transitions,  // [T,T] (log domain)
    const float* __restrict__ start_t,      // [T]
    const float* __restrict__ end_t,        // [T]
    float* __restrict__ out_per_batch)      // [B]
{
    const int b   = blockIdx.x;
    const int tid = threadIdx.x;
    const int w   = tid >> 6;     // wave 0..7
    const int l   = tid & 63;     // lane 0..63
    const int cl  = l & 15;       // column within wave
    const int kq  = l >> 4;       // K-quarter 0..3
    const int c   = 16 * w + cl;  // owned output column
    const int i0  = 32 * kq;      // start of this lane's i range

    __shared__ __align__(16) unsigned int p_lds[2][64]; // packed f16 P pairs
    __shared__ __align__(16) float        wmax[2][8];   // per-wave maxes
    __shared__ float redA[8], redB[8], redC[8];         // epilogue reductions
    __shared__ float msk_s[SEQ];

    // ---- E fragment: rows i0+2u, i0+2u+1 of column c, prob domain f16 ----
    half2v E[16];
    #pragma unroll
    for (int u = 0; u < 16; ++u) {
        float ea = transitions[(i0 + 2*u    ) * NT + c];
        float ob = transitions[(i0 + 2*u + 1) * NT + c];
        E[u] = half2v{(_Float16)__expf(ea), (_Float16)__expf(ob)};
    }

    for (int s = tid; s < SEQ; s += 512)
        msk_s[s] = masks[b * SEQ + s];

    // ---- init: P = exp(start), offset = 0 ----
    float cur = __expf(start_t[c]);
    float offset = 0.0f;

    {
        float curo = swap1_dpp(cur);
        if (kq == 0 && (cl & 1) == 0)
            p_lds[0][8*w + (cl >> 1)] = __builtin_bit_cast(unsigned int,
                __builtin_amdgcn_cvt_pkrtz(cur, curo));
        float wm = wave_max_dpp(cur);
        if (l == 0) wmax[0][w] = wm;
    }
    __syncthreads();

    float4 wa0 = *(const float4*)&wmax[0][0];
    float4 wb0 = *(const float4*)&wmax[0][4];
    float mx   = fmaxf(fmaxf(fmaxf(wa0.x, wa0.y), fmaxf(wa0.z, wa0.w)),
                       fmaxf(fmaxf(wb0.x, wb0.y), fmaxf(wb0.z, wb0.w)));
    float inv  = __builtin_amdgcn_rcpf(256.0f * mx);
    float offadd = __logf(mx) + 5.545177444479562f;   // log(256*mx)

    const float* eb  = emissions + (size_t)b * SEQ * NT;
    const float* mkp = masks + b * SEQ;

    // depth-4 rings: slot k holds em/mask for step s with s&3==k (scalar)
    float ring0 = eb[(size_t)0 * NT + c];
    float ring1 = eb[(size_t)1 * NT + c];
    float ring2 = eb[(size_t)2 * NT + c];
    float ring3 = eb[(size_t)3 * NT + c];
    float mr0 = mkp[0], mr1 = mkp[1], mr2 = mkp[2], mr3 = mkp[3];

    float ex = __expf(ring0) * inv;

    const float* emp = eb + 4 * NT + c;   // em[s+4] for s=0
    const float* mpp = mkp + 4;

    // main loop: steps 0..1019, unrolled x4 (ring slots static; BUF = s&1)
    for (int it = 0; it < (SEQ - 4) / 4; ++it) {
        CRF_STEP(ring0, ring1, mr0, true, 0, 0)
        CRF_STEP(ring1, ring2, mr1, true, 1, 1)
        CRF_STEP(ring2, ring3, mr2, true, 2, 0)
        CRF_STEP(ring3, ring0, mr3, true, 3, 1)
        emp += 4 * NT;
        mpp += 4;
    }
    // tail: steps 1020..1023 (no prefetch)
    CRF_STEP(ring0, ring1, mr0, false, 0, 0)
    CRF_STEP(ring1, ring2, mr1, false, 0, 1)
    CRF_STEP(ring2, ring3, mr2, false, 0, 0)
    CRF_STEP(ring3, ring3, mr3, false, 0, 1)

    // ---- log_z = offset + log( sum_j P_j * exp(end_j) ) ----
    // cur is replicated across the 4 K-quarters; count kq==0 only.
    float term = (kq == 0) ? cur * __expf(end_t[c]) : 0.0f;
    #pragma unroll
    for (int off = 32; off; off >>= 1)
        term += __shfl_xor(term, off);
    if (l == 0) redA[w] = term;

    // ---- gold-path score (512 threads, 2 s-iters each) ----
    const int tbase = b * SEQ;
    float sc = 0.0f, sm = 0.0f;
    for (int s = tid; s < SEQ; s += 512) {
        float m = msk_s[s];
        sm += m;
        if (s < SEQ - 1) {
            int tg  = tags[tbase + s];
            int tg1 = tags[tbase + s + 1];
            sc += eb[(size_t)s * NT + tg] * m;
            sc += transitions[tg * NT + tg1] * msk_s[s + 1];
        }
    }
    #pragma unroll
    for (int off = 32; off; off >>= 1) {
        sc += __shfl_xor(sc, off);
        sm += __shfl_xor(sm, off);
    }
    if (l == 0) { redB[w] = sc; redC[w] = sm; }
    __syncthreads();

    if (tid == 0) {
        float term_t = ((redA[0] + redA[1]) + (redA[2] + redA[3]))
                     + ((redA[4] + redA[5]) + (redA[6] + redA[7]));
        float log_z  = offset + __logf(term_t);
        float sct    = ((redB[0] + redB[1]) + (redB[2] + redB[3]))
                     + ((redB[4] + redB[5]) + (redB[6] + redB[7]));
        float smt    = ((redC[0] + redC[1]) + (redC[2] + redC[3]))
                     + ((redC[4] + redC[5]) + (redC[6] + redC[7]));
        int tg0 = tags[tbase];
        int tgl = tags[tbase + SEQ - 1];
        sct += start_t[tg0];
        int last_ix = (int)fmaxf(smt - 1.0f, 0.0f);
        float ml = msk_s[SEQ - 1];
        sct += eb[(size_t)last_ix * NT + tgl] * ml;
        sct += end_t[tgl] * ml;
        out_per_batch[b] = log_z - sct;
    }
}

// mean over batch -> scalar output
__global__ void crf_reduce_kernel(const float* __restrict__ pb, float* __restrict__ out)
{
    float v = pb[threadIdx.x];   // 256 threads, one per batch
    #pragma unroll
    for (int off = 32; off; off >>= 1)
        v += __shfl_xor(v, off);
    __shared__ float s4[4];
    if ((threadIdx.x & 63) == 0) s4[threadIdx.x >> 6] = v;
    __syncthreads();
    if (threadIdx.x == 0)
        out[0] = (s4[0] + s4[1] + s4[2] + s4[3]) * (1.0f / 256.0f);
}

extern "C" void kernel_launch(void* const* d_in, const int* in_sizes, int n_in,
                              void* d_out, int out_size, void* d_ws, size_t ws_size,
                              hipStream_t stream) {
    const float* emissions   = (const float*)d_in[0];
    const float* masks       = (const float*)d_in[1];
    const int*   tags        = (const int*)  d_in[2];
    const float* transitions = (const float*)d_in[3];
    const float* start_t     = (const float*)d_in[4];
    const float* end_t       = (const float*)d_in[5];
    float* per_batch = (float*)d_ws;

    crf_scan_kernel<<<NB, 512, 0, stream>>>(emissions, masks, tags, transitions,
                                            start_t, end_t, per_batch);
    crf_reduce_kernel<<<1, 256, 0, stream>>>(per_batch, (float*)d_out);
}